// Round 1
// baseline (506.700 us; speedup 1.0000x reference)
//
#include <hip/hip_runtime.h>

// StarLoss: mean over (B,N) of
//   (1/sqrt(lam1)+eps)*d1 + (1/sqrt(lam2)+eps)*d2 + 0.5*omega*(lam1+lam2)
// where d1,d2 are GLOBAL sums of squared rotated residuals. Decomposes into
// 5 scalar sums S1..S5; final = (S1*S3 + S2*S4 + 0.5*S5)/M.

#define NBLOCKS  2048
#define NTHREADS 256
#define NACC     5
#define M_ELEMS  16777216   // 4096*4096
#define EPS      1e-5
#define OMEGA    1.0

__device__ __forceinline__ float wave_reduce_f(float v) {
    #pragma unroll
    for (int off = 32; off > 0; off >>= 1) v += __shfl_down(v, off, 64);
    return v;
}

__global__ __launch_bounds__(NTHREADS) void star_partial(
    const float4* __restrict__ pred,   // (M/2) float4: 2 elements per vec
    const float4* __restrict__ cov,    // (M)   float4: 1 element per vec
    const float4* __restrict__ tgt,    // (M/2) float4
    float* __restrict__ partials,      // NBLOCKS * NACC
    int n_pairs)
{
    float s1 = 0.f, s2 = 0.f, s3 = 0.f, s4 = 0.f, s5 = 0.f;
    const int stride = gridDim.x * blockDim.x;

    for (int i = blockIdx.x * blockDim.x + threadIdx.x; i < n_pairs; i += stride) {
        float4 p  = pred[i];
        float4 t  = tgt[i];
        float4 c0 = cov[2 * i];
        float4 c1 = cov[2 * i + 1];

        #pragma unroll
        for (int e = 0; e < 2; ++e) {
            float a  = e ? c1.x : c0.x;
            float b  = e ? c1.y : c0.y;
            float d  = e ? c1.w : c0.w;
            float dx = (e ? p.z : p.x) - (e ? t.z : t.x);
            float dy = (e ? p.w : p.y) - (e ? t.w : t.y);

            float mean = 0.5f * (a + d);
            float hd   = 0.5f * (a - d);
            float delta = sqrtf(hd * hd + b * b);
            float lam1 = mean + delta;
            float lam2 = mean - delta;   // >= 0.1 by construction (PSD + 0.1*I)

            bool diag = fabsf(b) < 1e-12f;
            bool a_ge = (a >= d);
            float vx = diag ? (a_ge ? 1.0f : 0.0f) : b;
            float vy = diag ? (a_ge ? 0.0f : 1.0f) : (lam1 - a);
            float inv_n = rsqrtf(vx * vx + vy * vy);
            vx *= inv_n;
            vy *= inv_n;

            float r1 = vx * dx + vy * dy;
            float r2 = vx * dy - vy * dx;

            s1 += r1 * r1;
            s2 += r2 * r2;
            s3 += rsqrtf(lam1);
            s4 += rsqrtf(lam2);
            s5 += a + d;              // == lam1 + lam2 (trace)
        }
    }

    // wave64 shuffle reduce, then cross-wave via LDS
    float v[NACC] = {s1, s2, s3, s4, s5};
    #pragma unroll
    for (int k = 0; k < NACC; ++k) v[k] = wave_reduce_f(v[k]);

    __shared__ float red[NTHREADS / 64][NACC];
    const int lane = threadIdx.x & 63;
    const int wid  = threadIdx.x >> 6;
    if (lane == 0) {
        #pragma unroll
        for (int k = 0; k < NACC; ++k) red[wid][k] = v[k];
    }
    __syncthreads();
    if (threadIdx.x == 0) {
        #pragma unroll
        for (int k = 0; k < NACC; ++k) {
            float acc = 0.f;
            #pragma unroll
            for (int w = 0; w < NTHREADS / 64; ++w) acc += red[w][k];
            partials[blockIdx.x * NACC + k] = acc;
        }
    }
}

__global__ __launch_bounds__(NTHREADS) void star_final(
    const float* __restrict__ partials, float* __restrict__ out, int nblocks)
{
    double acc[NACC] = {0, 0, 0, 0, 0};
    for (int i = threadIdx.x; i < nblocks; i += NTHREADS) {
        #pragma unroll
        for (int k = 0; k < NACC; ++k) acc[k] += (double)partials[i * NACC + k];
    }

    // wave64 shuffle reduce in double, then cross-wave via LDS
    #pragma unroll
    for (int k = 0; k < NACC; ++k) {
        #pragma unroll
        for (int off = 32; off > 0; off >>= 1)
            acc[k] += __shfl_down(acc[k], off, 64);
    }

    __shared__ double red[NTHREADS / 64][NACC];
    const int lane = threadIdx.x & 63;
    const int wid  = threadIdx.x >> 6;
    if (lane == 0) {
        #pragma unroll
        for (int k = 0; k < NACC; ++k) red[wid][k] = acc[k];
    }
    __syncthreads();

    if (threadIdx.x == 0) {
        double S[NACC];
        #pragma unroll
        for (int k = 0; k < NACC; ++k) {
            double t = 0.0;
            #pragma unroll
            for (int w = 0; w < NTHREADS / 64; ++w) t += red[w][k];
            S[k] = t;
        }
        const double M  = (double)M_ELEMS;
        const double S3 = S[2] + M * EPS;   // sum of (1/sqrt(lam1) + eps)
        const double S4 = S[3] + M * EPS;
        double loss = (S[0] * S3 + S[1] * S4 + 0.5 * OMEGA * S[4]) / M;
        out[0] = (float)loss;
    }
}

extern "C" void kernel_launch(void* const* d_in, const int* in_sizes, int n_in,
                              void* d_out, int out_size, void* d_ws, size_t ws_size,
                              hipStream_t stream) {
    const float4* pred = (const float4*)d_in[0];   // (B,N,2)   = M*2 floats
    const float4* cov  = (const float4*)d_in[1];   // (B,N,2,2) = M*4 floats
    const float4* tgt  = (const float4*)d_in[2];   // (B,N,2)   = M*2 floats
    float* out      = (float*)d_out;
    float* partials = (float*)d_ws;                // NBLOCKS*NACC floats (40 KB)

    const int n_pairs = M_ELEMS / 2;               // 2 elements per float4 of pred/tgt

    star_partial<<<NBLOCKS, NTHREADS, 0, stream>>>(pred, cov, tgt, partials, n_pairs);
    star_final<<<1, NTHREADS, 0, stream>>>(partials, out, NBLOCKS);
}

// Round 2
// 505.946 us; speedup vs baseline: 1.0015x; 1.0015x over previous
//
#include <hip/hip_runtime.h>

// StarLoss: mean over (B,N) of
//   (1/sqrt(lam1)+eps)*d1 + (1/sqrt(lam2)+eps)*d2 + 0.5*omega*(lam1+lam2)
// where d1,d2 are GLOBAL sums. Decomposes into 5 scalar sums S1..S5;
// final = (S1*S3 + S2*S4 + 0.5*S5)/M.
//
// R2: latency-bound fix — 1M threads (4096 blocks), 4 quads (16 elements)
// per thread with static trip count, unroll 2 so ~256 B of loads in flight
// per thread. R1 measured 3.34 TB/s effective (VALUBusy 18%, HBM 21%):
// neither pipe saturated -> MLP was the limiter.

#define NBLOCKS  4096
#define NTHREADS 256
#define NACC     5
#define M_ELEMS  16777216              // 4096*4096
#define NQUADS   (M_ELEMS / 4)         // 4,194,304
#define ITERS    (NQUADS / (NBLOCKS * NTHREADS))   // = 4 exactly
#define EPS      1e-5
#define OMEGA    1.0

__device__ __forceinline__ float wave_reduce_f(float v) {
    #pragma unroll
    for (int off = 32; off > 0; off >>= 1) v += __shfl_down(v, off, 64);
    return v;
}

// one 2x2 eigen-element: cov float4 c = [a, b, b, d], residual (dx, dy)
__device__ __forceinline__ void star_elem(
    float4 c, float dx, float dy,
    float& s1, float& s2, float& s3, float& s4, float& s5)
{
    const float a = c.x, b = c.y, d = c.w;
    float mean  = 0.5f * (a + d);
    float hd    = 0.5f * (a - d);
    float delta = sqrtf(hd * hd + b * b);
    float lam1  = mean + delta;
    float lam2  = mean - delta;           // >= 0.1 (PSD + 0.1*I)

    bool diag = fabsf(b) < 1e-12f;
    bool a_ge = (a >= d);
    float vx = diag ? (a_ge ? 1.0f : 0.0f) : b;
    float vy = diag ? (a_ge ? 0.0f : 1.0f) : (lam1 - a);
    float inv_n = rsqrtf(vx * vx + vy * vy);
    vx *= inv_n;
    vy *= inv_n;

    float r1 = vx * dx + vy * dy;
    float r2 = vx * dy - vy * dx;

    s1 += r1 * r1;
    s2 += r2 * r2;
    s3 += rsqrtf(lam1);
    s4 += rsqrtf(lam2);
    s5 += a + d;                          // trace = lam1 + lam2
}

__global__ __launch_bounds__(NTHREADS) void star_partial(
    const float4* __restrict__ pred,   // M/2 float4 (2 elems each)
    const float4* __restrict__ cov,    // M float4   (1 elem each)
    const float4* __restrict__ tgt,    // M/2 float4
    float* __restrict__ partials)      // NBLOCKS * NACC
{
    float s1 = 0.f, s2 = 0.f, s3 = 0.f, s4 = 0.f, s5 = 0.f;
    const int tid = blockIdx.x * NTHREADS + threadIdx.x;

    // quad q covers elements 4q..4q+3: pred/tgt float4 {2q, 2q+1},
    // cov float4 {4q..4q+3}. 8 x 16B loads per iteration; unroll 2
    // keeps ~16 loads outstanding.
    #pragma unroll 2
    for (int k = 0; k < ITERS; ++k) {
        const int q = tid + k * (NBLOCKS * NTHREADS);
        float4 p0 = pred[2 * q];
        float4 p1 = pred[2 * q + 1];
        float4 t0 = tgt[2 * q];
        float4 t1 = tgt[2 * q + 1];
        float4 c0 = cov[4 * q];
        float4 c1 = cov[4 * q + 1];
        float4 c2 = cov[4 * q + 2];
        float4 c3 = cov[4 * q + 3];

        star_elem(c0, p0.x - t0.x, p0.y - t0.y, s1, s2, s3, s4, s5);
        star_elem(c1, p0.z - t0.z, p0.w - t0.w, s1, s2, s3, s4, s5);
        star_elem(c2, p1.x - t1.x, p1.y - t1.y, s1, s2, s3, s4, s5);
        star_elem(c3, p1.z - t1.z, p1.w - t1.w, s1, s2, s3, s4, s5);
    }

    float v[NACC] = {s1, s2, s3, s4, s5};
    #pragma unroll
    for (int k = 0; k < NACC; ++k) v[k] = wave_reduce_f(v[k]);

    __shared__ float red[NTHREADS / 64][NACC];
    const int lane = threadIdx.x & 63;
    const int wid  = threadIdx.x >> 6;
    if (lane == 0) {
        #pragma unroll
        for (int k = 0; k < NACC; ++k) red[wid][k] = v[k];
    }
    __syncthreads();
    if (threadIdx.x == 0) {
        #pragma unroll
        for (int k = 0; k < NACC; ++k) {
            float acc = 0.f;
            #pragma unroll
            for (int w = 0; w < NTHREADS / 64; ++w) acc += red[w][k];
            partials[blockIdx.x * NACC + k] = acc;
        }
    }
}

__global__ __launch_bounds__(NTHREADS) void star_final(
    const float* __restrict__ partials, float* __restrict__ out, int nblocks)
{
    double acc[NACC] = {0, 0, 0, 0, 0};
    for (int i = threadIdx.x; i < nblocks; i += NTHREADS) {
        #pragma unroll
        for (int k = 0; k < NACC; ++k) acc[k] += (double)partials[i * NACC + k];
    }

    #pragma unroll
    for (int k = 0; k < NACC; ++k) {
        #pragma unroll
        for (int off = 32; off > 0; off >>= 1)
            acc[k] += __shfl_down(acc[k], off, 64);
    }

    __shared__ double red[NTHREADS / 64][NACC];
    const int lane = threadIdx.x & 63;
    const int wid  = threadIdx.x >> 6;
    if (lane == 0) {
        #pragma unroll
        for (int k = 0; k < NACC; ++k) red[wid][k] = acc[k];
    }
    __syncthreads();

    if (threadIdx.x == 0) {
        double S[NACC];
        #pragma unroll
        for (int k = 0; k < NACC; ++k) {
            double t = 0.0;
            #pragma unroll
            for (int w = 0; w < NTHREADS / 64; ++w) t += red[w][k];
            S[k] = t;
        }
        const double M  = (double)M_ELEMS;
        const double S3 = S[2] + M * EPS;   // sum of (1/sqrt(lam1) + eps)
        const double S4 = S[3] + M * EPS;
        double loss = (S[0] * S3 + S[1] * S4 + 0.5 * OMEGA * S[4]) / M;
        out[0] = (float)loss;
    }
}

extern "C" void kernel_launch(void* const* d_in, const int* in_sizes, int n_in,
                              void* d_out, int out_size, void* d_ws, size_t ws_size,
                              hipStream_t stream) {
    const float4* pred = (const float4*)d_in[0];   // (B,N,2)   = M*2 floats
    const float4* cov  = (const float4*)d_in[1];   // (B,N,2,2) = M*4 floats
    const float4* tgt  = (const float4*)d_in[2];   // (B,N,2)   = M*2 floats
    float* out      = (float*)d_out;
    float* partials = (float*)d_ws;                // NBLOCKS*NACC floats (80 KB)

    star_partial<<<NBLOCKS, NTHREADS, 0, stream>>>(pred, cov, tgt, partials);
    star_final<<<1, NTHREADS, 0, stream>>>(partials, out, NBLOCKS);
}

// Round 4
// 504.713 us; speedup vs baseline: 1.0039x; 1.0024x over previous
//
#include <hip/hip_runtime.h>

// StarLoss: mean over (B,N) of
//   (1/sqrt(lam1)+eps)*d1 + (1/sqrt(lam2)+eps)*d2 + 0.5*omega*(lam1+lam2)
// where d1,d2 are GLOBAL sums. Decomposes into 5 scalar sums S1..S5;
// final = (S1*S3 + S2*S4 + 0.5*S5)/M.
//
// R4 = R3 with the compile fix: __builtin_nontemporal_load needs a native
// clang vector type, not HIP_vector_type<float,4>. Theory unchanged:
// read path pinned at ~3.34 TB/s (MSHR x latency cap), insensitive to MLP
// (R2) and coalescing (R1 vs R2); NT loads avoid evicting the L3-resident
// (restore-written) half of the inputs -> higher hit fraction -> lower
// average latency -> higher read BW.

#define NBLOCKS  4096
#define NTHREADS 256
#define NACC     5
#define M_ELEMS  16777216              // 4096*4096
#define NQUADS   (M_ELEMS / 4)         // 4,194,304
#define ITERS    (NQUADS / (NBLOCKS * NTHREADS))   // = 4 exactly
#define EPS      1e-5
#define OMEGA    1.0

typedef float f4 __attribute__((ext_vector_type(4)));   // native vector: NT-loadable

__device__ __forceinline__ f4 nt_load(const f4* p) {
    return __builtin_nontemporal_load(p);
}

__device__ __forceinline__ float wave_reduce_f(float v) {
    #pragma unroll
    for (int off = 32; off > 0; off >>= 1) v += __shfl_down(v, off, 64);
    return v;
}

// one 2x2 eigen-element: cov f4 c = [a, b, b, d], residual (dx, dy)
__device__ __forceinline__ void star_elem(
    f4 c, float dx, float dy,
    float& s1, float& s2, float& s3, float& s4, float& s5)
{
    const float a = c.x, b = c.y, d = c.w;
    float mean  = 0.5f * (a + d);
    float hd    = 0.5f * (a - d);
    float delta = sqrtf(hd * hd + b * b);
    float lam1  = mean + delta;
    float lam2  = mean - delta;           // >= 0.1 (PSD + 0.1*I)

    bool diag = fabsf(b) < 1e-12f;
    bool a_ge = (a >= d);
    float vx = diag ? (a_ge ? 1.0f : 0.0f) : b;
    float vy = diag ? (a_ge ? 0.0f : 1.0f) : (lam1 - a);
    float inv_n = rsqrtf(vx * vx + vy * vy);
    vx *= inv_n;
    vy *= inv_n;

    float r1 = vx * dx + vy * dy;
    float r2 = vx * dy - vy * dx;

    s1 += r1 * r1;
    s2 += r2 * r2;
    s3 += rsqrtf(lam1);
    s4 += rsqrtf(lam2);
    s5 += a + d;                          // trace = lam1 + lam2
}

__global__ __launch_bounds__(NTHREADS) void star_partial(
    const f4* __restrict__ pred,   // M/2 f4 (2 elems each)
    const f4* __restrict__ cov,    // M f4   (1 elem each)
    const f4* __restrict__ tgt,    // M/2 f4
    float* __restrict__ partials)  // NBLOCKS * NACC
{
    float s1 = 0.f, s2 = 0.f, s3 = 0.f, s4 = 0.f, s5 = 0.f;
    const int tid = blockIdx.x * NTHREADS + threadIdx.x;

    #pragma unroll 2
    for (int k = 0; k < ITERS; ++k) {
        const int q = tid + k * (NBLOCKS * NTHREADS);
        f4 p0 = nt_load(&pred[2 * q]);
        f4 p1 = nt_load(&pred[2 * q + 1]);
        f4 t0 = nt_load(&tgt[2 * q]);
        f4 t1 = nt_load(&tgt[2 * q + 1]);
        f4 c0 = nt_load(&cov[4 * q]);
        f4 c1 = nt_load(&cov[4 * q + 1]);
        f4 c2 = nt_load(&cov[4 * q + 2]);
        f4 c3 = nt_load(&cov[4 * q + 3]);

        star_elem(c0, p0.x - t0.x, p0.y - t0.y, s1, s2, s3, s4, s5);
        star_elem(c1, p0.z - t0.z, p0.w - t0.w, s1, s2, s3, s4, s5);
        star_elem(c2, p1.x - t1.x, p1.y - t1.y, s1, s2, s3, s4, s5);
        star_elem(c3, p1.z - t1.z, p1.w - t1.w, s1, s2, s3, s4, s5);
    }

    float v[NACC] = {s1, s2, s3, s4, s5};
    #pragma unroll
    for (int k = 0; k < NACC; ++k) v[k] = wave_reduce_f(v[k]);

    __shared__ float red[NTHREADS / 64][NACC];
    const int lane = threadIdx.x & 63;
    const int wid  = threadIdx.x >> 6;
    if (lane == 0) {
        #pragma unroll
        for (int k = 0; k < NACC; ++k) red[wid][k] = v[k];
    }
    __syncthreads();
    if (threadIdx.x == 0) {
        #pragma unroll
        for (int k = 0; k < NACC; ++k) {
            float acc = 0.f;
            #pragma unroll
            for (int w = 0; w < NTHREADS / 64; ++w) acc += red[w][k];
            partials[blockIdx.x * NACC + k] = acc;
        }
    }
}

__global__ __launch_bounds__(NTHREADS) void star_final(
    const float* __restrict__ partials, float* __restrict__ out, int nblocks)
{
    double acc[NACC] = {0, 0, 0, 0, 0};
    for (int i = threadIdx.x; i < nblocks; i += NTHREADS) {
        #pragma unroll
        for (int k = 0; k < NACC; ++k) acc[k] += (double)partials[i * NACC + k];
    }

    #pragma unroll
    for (int k = 0; k < NACC; ++k) {
        #pragma unroll
        for (int off = 32; off > 0; off >>= 1)
            acc[k] += __shfl_down(acc[k], off, 64);
    }

    __shared__ double red[NTHREADS / 64][NACC];
    const int lane = threadIdx.x & 63;
    const int wid  = threadIdx.x >> 6;
    if (lane == 0) {
        #pragma unroll
        for (int k = 0; k < NACC; ++k) red[wid][k] = acc[k];
    }
    __syncthreads();

    if (threadIdx.x == 0) {
        double S[NACC];
        #pragma unroll
        for (int k = 0; k < NACC; ++k) {
            double t = 0.0;
            #pragma unroll
            for (int w = 0; w < NTHREADS / 64; ++w) t += red[w][k];
            S[k] = t;
        }
        const double M  = (double)M_ELEMS;
        const double S3 = S[2] + M * EPS;   // sum of (1/sqrt(lam1) + eps)
        const double S4 = S[3] + M * EPS;
        double loss = (S[0] * S3 + S[1] * S4 + 0.5 * OMEGA * S[4]) / M;
        out[0] = (float)loss;
    }
}

extern "C" void kernel_launch(void* const* d_in, const int* in_sizes, int n_in,
                              void* d_out, int out_size, void* d_ws, size_t ws_size,
                              hipStream_t stream) {
    const f4* pred = (const f4*)d_in[0];   // (B,N,2)   = M*2 floats
    const f4* cov  = (const f4*)d_in[1];   // (B,N,2,2) = M*4 floats
    const f4* tgt  = (const f4*)d_in[2];   // (B,N,2)   = M*2 floats
    float* out      = (float*)d_out;
    float* partials = (float*)d_ws;        // NBLOCKS*NACC floats (80 KB)

    star_partial<<<NBLOCKS, NTHREADS, 0, stream>>>(pred, cov, tgt, partials);
    star_final<<<1, NTHREADS, 0, stream>>>(partials, out, NBLOCKS);
}